// Round 9
// baseline (306.042 us; speedup 1.0000x reference)
//
#include <hip/hip_runtime.h>

typedef _Float16 v8hf __attribute__((ext_vector_type(8)));
typedef float    v4f  __attribute__((ext_vector_type(4)));

#define MFMA16(a, b, c) __builtin_amdgcn_mfma_f32_16x16x32_f16((a), (b), (c), 0, 0, 0)

#define TT 512
#define BT 16      // batch rows per workgroup (= MFMA M)
#define NTH 512    // 8 waves: w0-3 = L1 (self-recurrence), w4-7 = prefetched consumers

// LDS map (bytes). Two 8KB parity blocks; ALL self-reads at rp, ALL writes at wp,
// ALL cross-layer inputs prefetched during the previous phase from that phase's rp.
//   block p at p*8192:  h1: +0    row stride 272 B (k: 0..99 h1, 100..111 fake, 112..113 x)
//                       h2: +4352 row stride 144 B
//                       h3: +6656 row stride  80 B
//   xst  at 16384: [t][b] f16x2, 64 B per t   (32 KB)
//   ring at 49152: [b][64][2] f32, 512 B per b (8 KB)
#define PBLK  8192u
#define H2OFF 4352u
#define H3OFF 6656u
#define XSTO  16384u
#define RINGO 49152u

__shared__ __align__(64) char SM[57344];

// batched tanh: 4 exp2 + 1 rcp per 4 values; med3 clamp |x|<=4.8 (err 1.35e-4).
__device__ __forceinline__ v4f tanh4(v4f r) {
    const float KS = 2.8853900817779268f;   // 2*log2(e)
    const float CL = 13.8498724f;           // 4.8 * KS
    float z0 = __builtin_amdgcn_fmed3f(r[0] * KS, -CL, CL);
    float z1 = __builtin_amdgcn_fmed3f(r[1] * KS, -CL, CL);
    float z2 = __builtin_amdgcn_fmed3f(r[2] * KS, -CL, CL);
    float z3 = __builtin_amdgcn_fmed3f(r[3] * KS, -CL, CL);
    float a0 = __builtin_amdgcn_exp2f(z0) + 1.f;
    float a1 = __builtin_amdgcn_exp2f(z1) + 1.f;
    float a2 = __builtin_amdgcn_exp2f(z2) + 1.f;
    float a3 = __builtin_amdgcn_exp2f(z3) + 1.f;
    float P = a0 * a1, Q = a2 * a3;
    float R = __builtin_amdgcn_rcpf(P * Q);
    float iP = Q * R, iQ = P * R;
    v4f t;
    t[0] = 1.f - 2.f * (a1 * iP);
    t[1] = 1.f - 2.f * (a0 * iP);
    t[2] = 1.f - 2.f * (a3 * iQ);
    t[3] = 1.f - 2.f * (a2 * iQ);
    return t;
}

__global__ __launch_bounds__(NTH)
void rnn3_pf(const float* __restrict__ xg,
             const float* __restrict__ Wih1, const float* __restrict__ Whh1,
             const float* __restrict__ bih1, const float* __restrict__ bhh1,
             const float* __restrict__ Wih2, const float* __restrict__ Whh2,
             const float* __restrict__ bih2, const float* __restrict__ bhh2,
             const float* __restrict__ Wih3, const float* __restrict__ Whh3,
             const float* __restrict__ bih3, const float* __restrict__ bhh3,
             const float* __restrict__ Wo1,  const float* __restrict__ bo1,
             const float* __restrict__ Wo2,  const float* __restrict__ bo2,
             float* __restrict__ outg)
{
    const int tid   = threadIdx.x;
    const int lane  = tid & 63;
    const int wid   = tid >> 6;       // SIMD = wid&3 -> pairs (0,4)(1,5)(2,6)(3,7)
    const int col   = lane & 15;
    const int g     = lane >> 4;
    const int bbase = blockIdx.x * BT;

    // ---------------- init: zero both parity state blocks, stage x ----------------
    {
        float4 z = {0.f, 0.f, 0.f, 0.f};
        float4* p4 = (float4*)SM;
        for (int i = tid; i < 1024; i += NTH) p4[i] = z;   // bytes [0, 16384)
        for (int i = tid; i < BT * TT * 2; i += NTH) {
            float v = xg[(size_t)bbase * (TT * 2) + i];
            int b = i >> 10, r = i & 1023, t = r >> 1, c = r & 1;
            *(_Float16*)(SM + XSTO + (unsigned)t * 64u + (unsigned)b * 4u + (unsigned)c * 2u) = (_Float16)v;
        }
    }

    // ---------------- weight fragments (registers) ----------------
    // B-frag convention: (lane,e) = W[j][k], j = tile_base + col, k = kt*32 + g*8 + e.
    v8hf F[12];
    #pragma unroll
    for (int i = 0; i < 12; ++i) F[i] = (v8hf)(_Float16)0.f;
    v8hf pf[2][4];
    #pragma unroll
    for (int i = 0; i < 4; ++i) { pf[0][i] = (v8hf)(_Float16)0.f; pf[1][i] = (v8hf)(_Float16)0.f; }
    float bb0 = 0.f, bb1 = 0.f;

    auto ldW = [&](const float* W, int rows, int cols, int j, int kt) -> v8hf {
        v8hf r;
        #pragma unroll
        for (int e = 0; e < 8; ++e) {
            const int k = kt * 32 + g * 8 + e;
            float v = (j < rows && k < cols) ? W[j * cols + k] : 0.f;
            r[e] = (_Float16)v;
        }
        return r;
    };
    auto ldW1 = [&](int j, int kt) -> v8hf {     // Whh1 (k<100) + x weights at k=112,113
        v8hf r;
        #pragma unroll
        for (int e = 0; e < 8; ++e) {
            const int k = kt * 32 + g * 8 + e;
            float v = 0.f;
            if (j < 100) {
                if (k < 100)       v = Whh1[j * 100 + k];
                else if (k == 112) v = Wih1[j * 2];
                else if (k == 113) v = Wih1[j * 2 + 1];
            }
            r[e] = (_Float16)v;
        }
        return r;
    };

    unsigned bRd = 0, bRd2 = 0, bRd3 = 0, bW1 = 0, bW2 = 0, bW3 = 0, bXw = 0, bRw = 0;
    unsigned xr = 0;

    if (wid < 3) {                     // L1 tiles 2w, 2w+1
        const int jA = 32 * wid + col;
        #pragma unroll
        for (int kt = 0; kt < 4; ++kt) { F[kt] = ldW1(jA, kt); F[4 + kt] = ldW1(jA + 16, kt); }
        bb0 = (jA < 100) ? bih1[jA] + bhh1[jA] : 0.f;
        bb1 = (jA + 16 < 100) ? bih1[jA + 16] + bhh1[jA + 16] : 0.f;
        bRd = (unsigned)col * 272u + (unsigned)g * 16u;
        bW1 = (unsigned)(4 * g) * 272u + (unsigned)jA * 2u;
    } else if (wid == 3) {             // L1 tile 6 + x-stage
        const int jA = 96 + col;
        #pragma unroll
        for (int kt = 0; kt < 4; ++kt) F[kt] = ldW1(jA, kt);
        bb0 = (jA < 100) ? bih1[jA] + bhh1[jA] : 0.f;
        bRd = (unsigned)col * 272u + (unsigned)g * 16u;
        bW1 = (unsigned)(4 * g) * 272u + (unsigned)jA * 2u;
        bXw = (unsigned)lane * 272u + 224u;
        xr  = XSTO + 64u + (unsigned)lane * 4u;
    } else if (wid < 6) {              // L2 tiles 2(w-4), 2(w-4)+1 (h1 prefetched)
        const int jA = 32 * (wid - 4) + col;
        #pragma unroll
        for (int kt = 0; kt < 4; ++kt) { F[kt] = ldW(Wih2, 60, 100, jA, kt); F[6 + kt] = ldW(Wih2, 60, 100, jA + 16, kt); }
        F[4]  = ldW(Whh2, 60, 60, jA, 0);       F[5]  = ldW(Whh2, 60, 60, jA, 1);
        F[10] = ldW(Whh2, 60, 60, jA + 16, 0);  F[11] = ldW(Whh2, 60, 60, jA + 16, 1);
        bb0 = (jA < 60) ? bih2[jA] + bhh2[jA] : 0.f;
        bb1 = (jA + 16 < 60) ? bih2[jA + 16] + bhh2[jA + 16] : 0.f;
        bRd  = (unsigned)col * 272u + (unsigned)g * 16u;     // h1 prefetch
        bRd2 = (unsigned)col * 144u + (unsigned)g * 16u;     // h2 self
        bW2  = (unsigned)(4 * g) * 144u + (unsigned)jA * 2u;
    } else if (wid == 6) {             // L3 tiles 0,1 (h2 prefetched)
        const int jA = col;
        F[0] = ldW(Wih3, 30, 60, jA, 0);       F[1] = ldW(Wih3, 30, 60, jA, 1);
        F[2] = ldW(Whh3, 30, 30, jA, 0);
        F[3] = ldW(Wih3, 30, 60, jA + 16, 0);  F[4] = ldW(Wih3, 30, 60, jA + 16, 1);
        F[5] = ldW(Whh3, 30, 30, jA + 16, 0);
        bb0 = (jA < 30) ? bih3[jA] + bhh3[jA] : 0.f;
        bb1 = (jA + 16 < 30) ? bih3[jA + 16] + bhh3[jA + 16] : 0.f;
        bRd2 = (unsigned)col * 144u + (unsigned)g * 16u;     // h2 prefetch
        bRd3 = (unsigned)col * 80u + (unsigned)g * 16u;      // h3 self
        bW3  = (unsigned)(4 * g) * 80u + (unsigned)jA * 2u;
    } else {                           // head (h3 prefetched) + ring + flush
        #pragma unroll
        for (int e = 0; e < 8; ++e) {  // W_eff = Wo2 @ Wo1 (2 x 30)
            const int k = g * 8 + e;
            float v = 0.f;
            if (col < 2 && k < 30) {
                #pragma unroll
                for (int u = 0; u < 10; ++u) v += Wo2[col * 10 + u] * Wo1[u * 30 + k];
            }
            F[0][e] = (_Float16)v;
        }
        if (col < 2) {
            float bv = bo2[col];
            #pragma unroll
            for (int u = 0; u < 10; ++u) bv += Wo2[col * 10 + u] * bo1[u];
            bb0 = bv;
        }
        bRd3 = (unsigned)col * 80u + (unsigned)g * 16u;
        bRw  = RINGO + (unsigned)(4 * g) * 512u + (unsigned)col * 4u;
    }

    __syncthreads();
    if (tid < BT)   // x_0 into h1 parity-0 block at k=112..113
        *(unsigned*)(SM + (unsigned)tid * 272u + 224u) =
            *(const unsigned*)(SM + XSTO + (unsigned)tid * 4u);
    __syncthreads();

    if (wid < 4) __builtin_amdgcn_s_setprio(1);   // L1 waves own the critical path

    auto flushfn = [&](int s) {        // w7: flush 32 head steps [s-39, s-8]
        const int tbase = s - 39;
        const unsigned rb = RINGO + (((unsigned)tbase & 63u) >> 1) * 16u;
        #pragma unroll
        for (int jj = 0; jj < 4; ++jj) {
            const int f = lane + 64 * jj;
            const int b = f >> 4, k = f & 15;
            float4 v = *(const float4*)(SM + rb + (unsigned)b * 512u + (unsigned)k * 16u);
            *(float4*)(outg + ((size_t)(bbase + b) * TT + tbase) * 2 + 4 * k) = v;
        }
    };

// phase S (parity RP = S&1): L1(S) | L2(S-2) | L3(S-4) | head(S-6) | x_{S+1} | flush.
// Self-reads at rp; writes at wp; prefetch (pf[RP^1]) loads rp data for phase S+1.
#define PHASE(RP, L1ON, L2ON, L3ON, HDON, XON, S) do {                                   \
    const unsigned RB_ = (RP) ? PBLK : 0u;                                               \
    const unsigned WB_ = (RP) ? 0u : PBLK;                                               \
    if (wid < 3) {                                                                       \
        if (L1ON) {                                                                      \
            v8hf A0 = *(const v8hf*)(SM + bRd + RB_ + 0u);                               \
            v8hf A1 = *(const v8hf*)(SM + bRd + RB_ + 64u);                              \
            v8hf A2 = *(const v8hf*)(SM + bRd + RB_ + 128u);                             \
            v8hf A3 = *(const v8hf*)(SM + bRd + RB_ + 192u);                             \
            { v4f p = {bb0, bb0, bb0, bb0}, q = {0.f, 0.f, 0.f, 0.f};                    \
              p = MFMA16(A0, F[0], p); q = MFMA16(A1, F[1], q);                          \
              p = MFMA16(A2, F[2], p); q = MFMA16(A3, F[3], q);                          \
              v4f r = tanh4(p + q);                                                      \
              *(_Float16*)(SM + bW1 + WB_ + 0u)   = (_Float16)r[0];                      \
              *(_Float16*)(SM + bW1 + WB_ + 272u) = (_Float16)r[1];                      \
              *(_Float16*)(SM + bW1 + WB_ + 544u) = (_Float16)r[2];                      \
              *(_Float16*)(SM + bW1 + WB_ + 816u) = (_Float16)r[3]; }                    \
            { v4f p = {bb1, bb1, bb1, bb1}, q = {0.f, 0.f, 0.f, 0.f};                    \
              p = MFMA16(A0, F[4], p); q = MFMA16(A1, F[5], q);                          \
              p = MFMA16(A2, F[6], p); q = MFMA16(A3, F[7], q);                          \
              v4f r = tanh4(p + q);                                                      \
              *(_Float16*)(SM + bW1 + WB_ + 32u)  = (_Float16)r[0];                      \
              *(_Float16*)(SM + bW1 + WB_ + 304u) = (_Float16)r[1];                      \
              *(_Float16*)(SM + bW1 + WB_ + 576u) = (_Float16)r[2];                      \
              *(_Float16*)(SM + bW1 + WB_ + 848u) = (_Float16)r[3]; }                    \
        }                                                                                \
    } else if (wid == 3) {                                                               \
        if (XON) {                                                                       \
            if (lane < 16) {                                                             \
                unsigned xv = *(const unsigned*)(SM + xr);                               \
                *(unsigned*)(SM + bXw + WB_) = xv;                                       \
            }                                                                            \
        }                                                                                \
        xr += 64u;                                                                       \
        if (L1ON) {                                                                      \
            v8hf A0 = *(const v8hf*)(SM + bRd + RB_ + 0u);                               \
            v8hf A1 = *(const v8hf*)(SM + bRd + RB_ + 64u);                              \
            v8hf A2 = *(const v8hf*)(SM + bRd + RB_ + 128u);                             \
            v8hf A3 = *(const v8hf*)(SM + bRd + RB_ + 192u);                             \
            v4f p = {bb0, bb0, bb0, bb0}, q = {0.f, 0.f, 0.f, 0.f};                      \
            p = MFMA16(A0, F[0], p); q = MFMA16(A1, F[1], q);                            \
            p = MFMA16(A2, F[2], p); q = MFMA16(A3, F[3], q);                            \
            v4f r = tanh4(p + q);                                                        \
            *(_Float16*)(SM + bW1 + WB_ + 0u)   = (_Float16)r[0];                        \
            *(_Float16*)(SM + bW1 + WB_ + 272u) = (_Float16)r[1];                        \
            *(_Float16*)(SM + bW1 + WB_ + 544u) = (_Float16)r[2];                        \
            *(_Float16*)(SM + bW1 + WB_ + 816u) = (_Float16)r[3];                        \
        }                                                                                \
    } else if (wid < 6) {                                                                \
        if (L2ON) {                                                                      \
            v8hf B0 = *(const v8hf*)(SM + bRd2 + RB_ + H2OFF + 0u);                      \
            v8hf B1 = *(const v8hf*)(SM + bRd2 + RB_ + H2OFF + 64u);                     \
            { v4f p = {bb0, bb0, bb0, bb0}, q = {0.f, 0.f, 0.f, 0.f};                    \
              p = MFMA16(pf[RP][0], F[0], p); q = MFMA16(pf[RP][1], F[1], q);            \
              p = MFMA16(pf[RP][2], F[2], p); q = MFMA16(pf[RP][3], F[3], q);            \
              p = MFMA16(B0, F[4], p);        q = MFMA16(B1, F[5], q);                   \
              v4f r = tanh4(p + q);                                                      \
              *(_Float16*)(SM + bW2 + WB_ + H2OFF + 0u)   = (_Float16)r[0];              \
              *(_Float16*)(SM + bW2 + WB_ + H2OFF + 144u) = (_Float16)r[1];              \
              *(_Float16*)(SM + bW2 + WB_ + H2OFF + 288u) = (_Float16)r[2];              \
              *(_Float16*)(SM + bW2 + WB_ + H2OFF + 432u) = (_Float16)r[3]; }            \
            { v4f p = {bb1, bb1, bb1, bb1}, q = {0.f, 0.f, 0.f, 0.f};                    \
              p = MFMA16(pf[RP][0], F[6], p); q = MFMA16(pf[RP][1], F[7], q);            \
              p = MFMA16(pf[RP][2], F[8], p); q = MFMA16(pf[RP][3], F[9], q);            \
              p = MFMA16(B0, F[10], p);       q = MFMA16(B1, F[11], q);                  \
              v4f r = tanh4(p + q);                                                      \
              *(_Float16*)(SM + bW2 + WB_ + H2OFF + 32u)  = (_Float16)r[0];              \
              *(_Float16*)(SM + bW2 + WB_ + H2OFF + 176u) = (_Float16)r[1];              \
              *(_Float16*)(SM + bW2 + WB_ + H2OFF + 320u) = (_Float16)r[2];              \
              *(_Float16*)(SM + bW2 + WB_ + H2OFF + 464u) = (_Float16)r[3]; }            \
        }                                                                                \
        pf[(RP) ^ 1][0] = *(const v8hf*)(SM + bRd + RB_ + 0u);                           \
        pf[(RP) ^ 1][1] = *(const v8hf*)(SM + bRd + RB_ + 64u);                          \
        pf[(RP) ^ 1][2] = *(const v8hf*)(SM + bRd + RB_ + 128u);                         \
        pf[(RP) ^ 1][3] = *(const v8hf*)(SM + bRd + RB_ + 192u);                         \
    } else if (wid == 6) {                                                               \
        if (L3ON) {                                                                      \
            v8hf C0 = *(const v8hf*)(SM + bRd3 + RB_ + H3OFF);                           \
            { v4f p = {bb0, bb0, bb0, bb0}, q = {0.f, 0.f, 0.f, 0.f};                    \
              p = MFMA16(pf[RP][0], F[0], p); q = MFMA16(pf[RP][1], F[1], q);            \
              p = MFMA16(C0, F[2], p);                                                   \
              v4f r = tanh4(p + q);                                                      \
              *(_Float16*)(SM + bW3 + WB_ + H3OFF + 0u)   = (_Float16)r[0];              \
              *(_Float16*)(SM + bW3 + WB_ + H3OFF + 80u)  = (_Float16)r[1];              \
              *(_Float16*)(SM + bW3 + WB_ + H3OFF + 160u) = (_Float16)r[2];              \
              *(_Float16*)(SM + bW3 + WB_ + H3OFF + 240u) = (_Float16)r[3]; }            \
            { v4f p = {bb1, bb1, bb1, bb1}, q = {0.f, 0.f, 0.f, 0.f};                    \
              p = MFMA16(pf[RP][0], F[3], p); q = MFMA16(pf[RP][1], F[4], q);            \
              p = MFMA16(C0, F[5], p);                                                   \
              v4f r = tanh4(p + q);                                                      \
              *(_Float16*)(SM + bW3 + WB_ + H3OFF + 32u)  = (_Float16)r[0];              \
              *(_Float16*)(SM + bW3 + WB_ + H3OFF + 112u) = (_Float16)r[1];              \
              *(_Float16*)(SM + bW3 + WB_ + H3OFF + 192u) = (_Float16)r[2];              \
              *(_Float16*)(SM + bW3 + WB_ + H3OFF + 272u) = (_Float16)r[3]; }            \
        }                                                                                \
        pf[(RP) ^ 1][0] = *(const v8hf*)(SM + bRd2 + RB_ + H2OFF + 0u);                  \
        pf[(RP) ^ 1][1] = *(const v8hf*)(SM + bRd2 + RB_ + H2OFF + 64u);                 \
    } else {                                                                             \
        if (HDON) {                                                                      \
            v4f o = {bb0, bb0, bb0, bb0};                                                \
            o = MFMA16(pf[RP][0], F[0], o);                                              \
            const unsigned so = (((unsigned)(S) - 6u) & 63u) * 8u;                       \
            if (col < 2) {                                                               \
                *(float*)(SM + bRw + so + 0u)    = o[0];                                 \
                *(float*)(SM + bRw + so + 512u)  = o[1];                                 \
                *(float*)(SM + bRw + so + 1024u) = o[2];                                 \
                *(float*)(SM + bRw + so + 1536u) = o[3];                                 \
            }                                                                            \
        }                                                                                \
        pf[(RP) ^ 1][0] = *(const v8hf*)(SM + bRd3 + RB_ + H3OFF);                       \
        if ((S) >= 39 && (((S) - 39) & 31) == 0) flushfn((S));                           \
    }                                                                                    \
    __syncthreads();                                                                     \
} while (0)

    // prologue (pipeline fill; prefetches run unconditionally)
    PHASE(0, 1, 0, 0, 0, 1, 0);
    PHASE(1, 1, 0, 0, 0, 1, 1);
    PHASE(0, 1, 1, 0, 0, 1, 2);
    PHASE(1, 1, 1, 0, 0, 1, 3);
    PHASE(0, 1, 1, 1, 0, 1, 4);
    PHASE(1, 1, 1, 1, 0, 1, 5);
    // steady state: guard-free, compile-time parity
    for (int s = 6; s < 510; s += 2) {
        PHASE(0, 1, 1, 1, 1, 1, s);
        PHASE(1, 1, 1, 1, 1, 1, s + 1);
    }
    // epilogue (pipeline drain)
    PHASE(0, 1, 1, 1, 1, 1, 510);
    PHASE(1, 1, 1, 1, 1, 0, 511);
    PHASE(0, 0, 1, 1, 1, 0, 512);
    PHASE(1, 0, 1, 1, 1, 0, 513);
    PHASE(0, 0, 0, 1, 1, 0, 514);
    PHASE(1, 0, 0, 1, 1, 0, 515);
    PHASE(0, 0, 0, 0, 1, 0, 516);
    PHASE(1, 0, 0, 0, 1, 0, 517);
    PHASE(0, 0, 0, 0, 0, 0, 518);
    PHASE(1, 0, 0, 0, 0, 0, 519);   // final flush (tbase = 480)
}

extern "C" void kernel_launch(void* const* d_in, const int* in_sizes, int n_in,
                              void* d_out, int out_size, void* d_ws, size_t ws_size,
                              hipStream_t stream) {
    (void)in_sizes; (void)n_in; (void)d_ws; (void)ws_size; (void)out_size;
    const float* x     = (const float*)d_in[0];
    const float* W_ih1 = (const float*)d_in[1];
    const float* W_hh1 = (const float*)d_in[2];
    const float* b_ih1 = (const float*)d_in[3];
    const float* b_hh1 = (const float*)d_in[4];
    const float* W_ih2 = (const float*)d_in[5];
    const float* W_hh2 = (const float*)d_in[6];
    const float* b_ih2 = (const float*)d_in[7];
    const float* b_hh2 = (const float*)d_in[8];
    const float* W_ih3 = (const float*)d_in[9];
    const float* W_hh3 = (const float*)d_in[10];
    const float* b_ih3 = (const float*)d_in[11];
    const float* b_hh3 = (const float*)d_in[12];
    const float* W_o1  = (const float*)d_in[13];
    const float* b_o1  = (const float*)d_in[14];
    const float* W_o2  = (const float*)d_in[15];
    const float* b_o2  = (const float*)d_in[16];
    float* out = (float*)d_out;

    rnn3_pf<<<2048 / BT, NTH, 0, stream>>>(
        x, W_ih1, W_hh1, b_ih1, b_hh1,
        W_ih2, W_hh2, b_ih2, b_hh2,
        W_ih3, W_hh3, b_ih3, b_hh3,
        W_o1, b_o1, W_o2, b_o2, out);
}